// Round 1
// baseline (21993.750 us; speedup 1.0000x reference)
//
#include <hip/hip_runtime.h>

#define NN 50000
#define EE 800000
#define LL 800000
#define DD 128
#define WSZ (DD * DD)

// ---------- order-preserving float <-> uint map for atomic max ----------
__device__ __forceinline__ unsigned fmap(float x) {
    unsigned u = __float_as_uint(x);
    return (u & 0x80000000u) ? ~u : (u | 0x80000000u);
}
__device__ __forceinline__ float funmap(unsigned u) {
    return (u & 0x80000000u) ? __uint_as_float(u & 0x7fffffffu) : __uint_as_float(~u);
}

// ---------- scatter-add: dst[didx[e]] += src[sidx[e]] (rows of 128 f32) ----------
// 32 threads per edge, float4 per thread.
__global__ __launch_bounds__(256) void scatter_add_kernel(
    const float* __restrict__ src, const int* __restrict__ sidx,
    const int* __restrict__ didx, float* __restrict__ dst, int n)
{
    int tid = blockIdx.x * 256 + threadIdx.x;
    int e = tid >> 5;
    if (e >= n) return;
    int q = (tid & 31) << 2;
    int s = sidx[e];
    int d = didx[e];
    float4 v = *reinterpret_cast<const float4*>(src + (size_t)s * DD + q);
    float* dp = dst + (size_t)d * DD + q;
    atomicAdd(dp + 0, v.x);
    atomicAdd(dp + 1, v.y);
    atomicAdd(dp + 2, v.z);
    atomicAdd(dp + 3, v.w);
}

// ---------- fused sage update: out = norm(x@Wc + a0@Wn + a1@We + biases), leaky ----------
// Block: 256 threads, 32 rows x 128 cols. Thread t: cols {j2, j2+64}, rows g*8..g*8+7.
// One wave == one row-group g -> LDS reads of x are same-address broadcasts.
// x/out may alias (in-place safe: row-local dependence only) -> no __restrict__ on them.
__global__ __launch_bounds__(256) void sage_update_kernel(
    const float* x, const float* __restrict__ a0, const float* __restrict__ a1,
    const float* __restrict__ Wc, const float* __restrict__ Wn, const float* __restrict__ We,
    const float* __restrict__ bc, const float* __restrict__ bn, const float* __restrict__ be,
    float* out, int M, int act)
{
    __shared__ float sm[32 * DD];
    const int t = threadIdx.x;
    const int j2 = t & 63;
    const int g = t >> 6;
    const int block_row = blockIdx.x * 32;
    const int rows_here = min(32, M - block_row);

    float acc0[8], acc1[8];
#pragma unroll
    for (int r = 0; r < 8; ++r) { acc0[r] = 0.f; acc1[r] = 0.f; }

    const float* srcs[3] = { x, a0, a1 };
    const float* Ws[3]   = { Wc, Wn, We };

    for (int s = 0; s < 3; ++s) {
        __syncthreads();
        for (int idx = t; idx < 32 * 32; idx += 256) {
            int rr = idx >> 5;
            int c4 = (idx & 31) << 2;
            float4 v = make_float4(0.f, 0.f, 0.f, 0.f);
            if (rr < rows_here)
                v = *reinterpret_cast<const float4*>(srcs[s] + (size_t)(block_row + rr) * DD + c4);
            *reinterpret_cast<float4*>(&sm[rr * DD + c4]) = v;
        }
        __syncthreads();
        const float* __restrict__ W = Ws[s];
#pragma unroll 4
        for (int k = 0; k < DD; ++k) {
            float w0 = W[k * DD + j2];
            float w1 = W[k * DD + j2 + 64];
#pragma unroll
            for (int r = 0; r < 8; ++r) {
                float xv = sm[(g * 8 + r) * DD + k];
                acc0[r] = fmaf(xv, w0, acc0[r]);
                acc1[r] = fmaf(xv, w1, acc1[r]);
            }
        }
    }

    const float b0 = bc[j2] + bn[j2] + be[j2];
    const float b1 = bc[j2 + 64] + bn[j2 + 64] + be[j2 + 64];

#pragma unroll
    for (int r = 0; r < 8; ++r) {
        float v0 = acc0[r] + b0;
        float v1 = acc1[r] + b1;
        // row L2 norm: the 128 values of this row live in this wave (64 lanes x 2 cols)
        float ss = v0 * v0 + v1 * v1;
#pragma unroll
        for (int m = 32; m > 0; m >>= 1) ss += __shfl_xor(ss, m);
        float inv = 1.0f / fmaxf(sqrtf(ss), 1e-12f);
        v0 *= inv; v1 *= inv;
        if (act) {
            v0 = v0 >= 0.f ? v0 : 0.01f * v0;
            v1 = v1 >= 0.f ? v1 : 0.01f * v1;
        }
        if (g * 8 + r < rows_here) {
            size_t row = (size_t)(block_row + g * 8 + r);
            out[row * DD + j2]      = v0;
            out[row * DD + j2 + 64] = v1;
        }
    }
}

// ---------- final linear: out = x@W + b, plus column-max into colmax (fmap'd) ----------
__global__ __launch_bounds__(256) void out_linear_kernel(
    const float* __restrict__ x, const float* __restrict__ W, const float* __restrict__ bias,
    float* __restrict__ out, unsigned* __restrict__ colmax, int M)
{
    __shared__ float sm[32 * DD];
    __shared__ float cmx[4][DD];
    const int t = threadIdx.x;
    const int j2 = t & 63;
    const int g = t >> 6;
    const int block_row = blockIdx.x * 32;
    const int rows_here = min(32, M - block_row);

    float acc0[8], acc1[8];
#pragma unroll
    for (int r = 0; r < 8; ++r) { acc0[r] = 0.f; acc1[r] = 0.f; }

    for (int idx = t; idx < 32 * 32; idx += 256) {
        int rr = idx >> 5;
        int c4 = (idx & 31) << 2;
        float4 v = make_float4(0.f, 0.f, 0.f, 0.f);
        if (rr < rows_here)
            v = *reinterpret_cast<const float4*>(x + (size_t)(block_row + rr) * DD + c4);
        *reinterpret_cast<float4*>(&sm[rr * DD + c4]) = v;
    }
    __syncthreads();
#pragma unroll 4
    for (int k = 0; k < DD; ++k) {
        float w0 = W[k * DD + j2];
        float w1 = W[k * DD + j2 + 64];
#pragma unroll
        for (int r = 0; r < 8; ++r) {
            float xv = sm[(g * 8 + r) * DD + k];
            acc0[r] = fmaf(xv, w0, acc0[r]);
            acc1[r] = fmaf(xv, w1, acc1[r]);
        }
    }

    const float b0 = bias[j2];
    const float b1 = bias[j2 + 64];
    float m0 = -3.402823466e38f, m1 = -3.402823466e38f;
#pragma unroll
    for (int r = 0; r < 8; ++r) {
        float v0 = acc0[r] + b0;
        float v1 = acc1[r] + b1;
        if (g * 8 + r < rows_here) {
            size_t row = (size_t)(block_row + g * 8 + r);
            out[row * DD + j2]      = v0;
            out[row * DD + j2 + 64] = v1;
            m0 = fmaxf(m0, v0);
            m1 = fmaxf(m1, v1);
        }
    }
    cmx[g][j2]      = m0;
    cmx[g][j2 + 64] = m1;
    __syncthreads();
    if (t < DD) {
        float mm = fmaxf(fmaxf(cmx[0][t], cmx[1][t]), fmaxf(cmx[2][t], cmx[3][t]));
        atomicMax(&colmax[t], fmap(mm));
    }
}

__global__ void finalize_kernel(const unsigned* __restrict__ colmax, float* __restrict__ pooled)
{
    int j = threadIdx.x;
    if (j < DD) pooled[j] = funmap(colmax[j]) + funmap(colmax[DD + j]);
}

extern "C" void kernel_launch(void* const* d_in, const int* in_sizes, int n_in,
                              void* d_out, int out_size, void* d_ws, size_t ws_size,
                              hipStream_t stream)
{
    const float* nf_in      = (const float*)d_in[0];
    const float* ef_in      = (const float*)d_in[1];
    const float* node_Wc    = (const float*)d_in[2];
    const float* node_bc    = (const float*)d_in[3];
    const float* node_Wn    = (const float*)d_in[4];
    const float* node_bn    = (const float*)d_in[5];
    const float* node_We    = (const float*)d_in[6];
    const float* node_be    = (const float*)d_in[7];
    const float* edge_Wc    = (const float*)d_in[8];
    const float* edge_bc    = (const float*)d_in[9];
    const float* edge_Wn    = (const float*)d_in[10];
    const float* edge_bn    = (const float*)d_in[11];
    const float* edge_We    = (const float*)d_in[12];
    const float* edge_be    = (const float*)d_in[13];
    const float* W_node_out = (const float*)d_in[14];
    const float* b_node_out = (const float*)d_in[15];
    const float* W_edge_out = (const float*)d_in[16];
    const float* b_edge_out = (const float*)d_in[17];
    const int* edge_index        = (const int*)d_in[18];
    const int* line_edge_index   = (const int*)d_in[19];
    const int* node_edge_index   = (const int*)d_in[20];
    const int* node_edge_scatter = (const int*)d_in[21];
    const int* edge_node_index   = (const int*)d_in[22];
    const int* edge_node_scatter = (const int*)d_in[23];

    const size_t ND = (size_t)NN * DD;
    const size_t ED = (size_t)EE * DD;

    float* nfbuf = (float*)d_ws;
    float* efbuf = nfbuf + ND;
    float* aggN0 = efbuf + ED;
    float* aggN1 = aggN0 + ND;
    float* aggE0 = aggN1 + ND;
    float* aggE1 = aggE0 + ED;
    unsigned* colmax = (unsigned*)(aggE1 + ED);

    float* tn = (float*)d_out + DD;
    float* te = tn + ND;

    const int scatE_blocks = (EE * 32 + 255) / 256;
    const int scatL_blocks = (LL * 32 + 255) / 256;
    const int gemmN_blocks = (NN + 31) / 32;
    const int gemmE_blocks = (EE + 31) / 32;

    for (int i = 0; i < 3; ++i) {
        const float* nf = (i == 0) ? nf_in : nfbuf;
        const float* ef = (i == 0) ? ef_in : efbuf;
        hipMemsetAsync(aggN0, 0, ND * sizeof(float), stream);
        hipMemsetAsync(aggN1, 0, ND * sizeof(float), stream);
        hipMemsetAsync(aggE0, 0, ED * sizeof(float), stream);
        hipMemsetAsync(aggE1, 0, ED * sizeof(float), stream);

        // node aggregations
        scatter_add_kernel<<<scatE_blocks, 256, 0, stream>>>(nf, edge_index, edge_index + EE, aggN0, EE);
        scatter_add_kernel<<<scatE_blocks, 256, 0, stream>>>(ef, node_edge_index, node_edge_scatter, aggN1, EE);
        // edge aggregations (both read OLD nf/ef -> do before updates)
        scatter_add_kernel<<<scatL_blocks, 256, 0, stream>>>(ef, line_edge_index, line_edge_index + LL, aggE0, LL);
        scatter_add_kernel<<<scatL_blocks, 256, 0, stream>>>(nf, edge_node_index, edge_node_scatter, aggE1, LL);

        int act = (i < 2) ? 1 : 0;
        sage_update_kernel<<<gemmN_blocks, 256, 0, stream>>>(
            nf, aggN0, aggN1,
            node_Wc + (size_t)i * WSZ, node_Wn + (size_t)i * WSZ, node_We + (size_t)i * WSZ,
            node_bc + (size_t)i * DD,  node_bn + (size_t)i * DD,  node_be + (size_t)i * DD,
            nfbuf, NN, act);
        sage_update_kernel<<<gemmE_blocks, 256, 0, stream>>>(
            ef, aggE0, aggE1,
            edge_Wc + (size_t)i * WSZ, edge_Wn + (size_t)i * WSZ, edge_We + (size_t)i * WSZ,
            edge_bc + (size_t)i * DD,  edge_bn + (size_t)i * DD,  edge_be + (size_t)i * DD,
            efbuf, EE, act);
    }

    hipMemsetAsync(colmax, 0, 2 * DD * sizeof(unsigned), stream);
    out_linear_kernel<<<gemmN_blocks, 256, 0, stream>>>(nfbuf, W_node_out, b_node_out, tn, colmax, NN);
    out_linear_kernel<<<gemmE_blocks, 256, 0, stream>>>(efbuf, W_edge_out, b_edge_out, te, colmax + DD, EE);
    finalize_kernel<<<1, DD, 0, stream>>>(colmax, (float*)d_out);
}

// Round 2
// 7833.228 us; speedup vs baseline: 2.8078x; 2.8078x over previous
//
#include <hip/hip_runtime.h>

#define NN 50000
#define EE 800000
#define LL 800000
#define DD 128
#define WSZ (DD * DD)

// ---------- order-preserving float <-> uint map for atomic max ----------
__device__ __forceinline__ unsigned fmap(float x) {
    unsigned u = __float_as_uint(x);
    return (u & 0x80000000u) ? ~u : (u | 0x80000000u);
}
__device__ __forceinline__ float funmap(unsigned u) {
    return (u & 0x80000000u) ? __uint_as_float(u & 0x7fffffffu) : __uint_as_float(~u);
}

// ====================== CSR build ======================
__global__ __launch_bounds__(256) void hist_kernel(
    const int* __restrict__ dest, int n, int* __restrict__ cnt)
{
    int i = blockIdx.x * 256 + threadIdx.x;
    if (i < n) atomicAdd(&cnt[dest[i]], 1);
}

// block scans 2048 elements (256 thr x 8); writes exclusive-scanned chunk + block total
__global__ __launch_bounds__(256) void scan1_kernel(
    const int* __restrict__ in, int n, int* __restrict__ out, int* __restrict__ bsum)
{
    __shared__ int ts[256];
    const int tid = threadIdx.x;
    const int base = blockIdx.x * 2048 + tid * 8;
    int v[8]; int s = 0;
#pragma unroll
    for (int k = 0; k < 8; ++k) { v[k] = (base + k < n) ? in[base + k] : 0; s += v[k]; }
    ts[tid] = s;
    __syncthreads();
    for (int off = 1; off < 256; off <<= 1) {
        int y = (tid >= off) ? ts[tid - off] : 0;
        __syncthreads();
        ts[tid] += y;
        __syncthreads();
    }
    int excl = ts[tid] - s;                 // exclusive prefix within block
    if (tid == 255) bsum[blockIdx.x] = ts[255];
    int run = excl;
#pragma unroll
    for (int k = 0; k < 8; ++k) { if (base + k < n) out[base + k] = run; run += v[k]; }
}

// single-block exclusive scan of block sums (nb <= 512; max here is 391)
__global__ __launch_bounds__(512) void scan2_kernel(int* bsum, int nb)
{
    __shared__ int ts[512];
    const int tid = threadIdx.x;
    int v = (tid < nb) ? bsum[tid] : 0;
    ts[tid] = v;
    __syncthreads();
    for (int off = 1; off < 512; off <<= 1) {
        int y = (tid >= off) ? ts[tid - off] : 0;
        __syncthreads();
        ts[tid] += y;
        __syncthreads();
    }
    if (tid < nb) bsum[tid] = ts[tid] - v;
}

__global__ __launch_bounds__(256) void scan3_kernel(
    int* __restrict__ rs, int m, const int* __restrict__ bsum, int total)
{
    int i = blockIdx.x * 256 + threadIdx.x;
    if (i < m) rs[i] += bsum[i >> 11];
    else if (i == m) rs[m] = total;
}

__global__ __launch_bounds__(256) void fill_kernel(
    const int* __restrict__ dest, const int* __restrict__ srcv, int n,
    int* __restrict__ cursor, int* __restrict__ list)
{
    int i = blockIdx.x * 256 + threadIdx.x;
    if (i < n) {
        int p = atomicAdd(&cursor[dest[i]], 1);
        list[p] = srcv[i];
    }
}

// ====================== fused sage: gather-aggregate + 3x GEMM + norm + act ======================
// Block: 256 threads, 32 output rows. Thread t: cols {j2, j2+64}, rows g*8..g*8+7 (g = wave id).
// s=0 stages x rows; s=1,2 build aggregation rows on the fly from CSR (no agg buffers, no atomics).
__global__ __launch_bounds__(256) void sage_fused_kernel(
    const float* __restrict__ x,
    const float* __restrict__ src0, const int* __restrict__ rs0, const int* __restrict__ ls0,
    const float* __restrict__ src1, const int* __restrict__ rs1, const int* __restrict__ ls1,
    const float* __restrict__ Wc, const float* __restrict__ Wn, const float* __restrict__ We,
    const float* __restrict__ bc, const float* __restrict__ bn, const float* __restrict__ be,
    float* __restrict__ out, int M, int act)
{
    __shared__ float sm[32 * DD];
    const int t = threadIdx.x;
    const int j2 = t & 63;
    const int g = t >> 6;
    const int block_row = blockIdx.x * 32;
    const int rows_here = min(32, M - block_row);

    float acc0[8], acc1[8];
#pragma unroll
    for (int r = 0; r < 8; ++r) { acc0[r] = 0.f; acc1[r] = 0.f; }

    for (int s = 0; s < 3; ++s) {
        __syncthreads();
        if (s == 0) {
            for (int idx = t; idx < 32 * 32; idx += 256) {
                int rr = idx >> 5;
                int c4 = (idx & 31) << 2;
                float4 v = make_float4(0.f, 0.f, 0.f, 0.f);
                if (rr < rows_here)
                    v = *reinterpret_cast<const float4*>(x + (size_t)(block_row + rr) * DD + c4);
                *reinterpret_cast<float4*>(&sm[rr * DD + c4]) = v;
            }
        } else {
            const float* __restrict__ src = (s == 1) ? src0 : src1;
            const int*   __restrict__ rs  = (s == 1) ? rs0  : rs1;
            const int*   __restrict__ ls  = (s == 1) ? ls0  : ls1;
            // wave g aggregates rows g*8..g*8+7; lane covers 2 consecutive cols
            for (int r = 0; r < 8; ++r) {
                int rr = g * 8 + r;
                int d = block_row + rr;
                float2 a = make_float2(0.f, 0.f);
                if (d < M) {
                    int beg = rs[d], end = rs[d + 1];
                    for (int j = beg; j < end; ++j) {
                        int si = ls[j];
                        float2 v = *reinterpret_cast<const float2*>(src + (size_t)si * DD + j2 * 2);
                        a.x += v.x; a.y += v.y;
                    }
                }
                *reinterpret_cast<float2*>(&sm[rr * DD + j2 * 2]) = a;
            }
        }
        __syncthreads();
        const float* __restrict__ W = (s == 0) ? Wc : ((s == 1) ? Wn : We);
#pragma unroll 4
        for (int k = 0; k < DD; ++k) {
            float w0 = W[k * DD + j2];
            float w1 = W[k * DD + j2 + 64];
#pragma unroll
            for (int r = 0; r < 8; ++r) {
                float xv = sm[(g * 8 + r) * DD + k];
                acc0[r] = fmaf(xv, w0, acc0[r]);
                acc1[r] = fmaf(xv, w1, acc1[r]);
            }
        }
    }

    const float b0 = bc[j2] + bn[j2] + be[j2];
    const float b1 = bc[j2 + 64] + bn[j2 + 64] + be[j2 + 64];

#pragma unroll
    for (int r = 0; r < 8; ++r) {
        float v0 = acc0[r] + b0;
        float v1 = acc1[r] + b1;
        float ss = v0 * v0 + v1 * v1;
#pragma unroll
        for (int m = 32; m > 0; m >>= 1) ss += __shfl_xor(ss, m);
        float inv = 1.0f / fmaxf(sqrtf(ss), 1e-12f);
        v0 *= inv; v1 *= inv;
        if (act) {
            v0 = v0 >= 0.f ? v0 : 0.01f * v0;
            v1 = v1 >= 0.f ? v1 : 0.01f * v1;
        }
        if (g * 8 + r < rows_here) {
            size_t row = (size_t)(block_row + g * 8 + r);
            out[row * DD + j2]      = v0;
            out[row * DD + j2 + 64] = v1;
        }
    }
}

// ---------- final linear: out = x@W + b, plus column-max into colmax (fmap'd) ----------
__global__ __launch_bounds__(256) void out_linear_kernel(
    const float* __restrict__ x, const float* __restrict__ W, const float* __restrict__ bias,
    float* __restrict__ out, unsigned* __restrict__ colmax, int M)
{
    __shared__ float sm[32 * DD];
    __shared__ float cmx[4][DD];
    const int t = threadIdx.x;
    const int j2 = t & 63;
    const int g = t >> 6;
    const int block_row = blockIdx.x * 32;
    const int rows_here = min(32, M - block_row);

    float acc0[8], acc1[8];
#pragma unroll
    for (int r = 0; r < 8; ++r) { acc0[r] = 0.f; acc1[r] = 0.f; }

    for (int idx = t; idx < 32 * 32; idx += 256) {
        int rr = idx >> 5;
        int c4 = (idx & 31) << 2;
        float4 v = make_float4(0.f, 0.f, 0.f, 0.f);
        if (rr < rows_here)
            v = *reinterpret_cast<const float4*>(x + (size_t)(block_row + rr) * DD + c4);
        *reinterpret_cast<float4*>(&sm[rr * DD + c4]) = v;
    }
    __syncthreads();
#pragma unroll 4
    for (int k = 0; k < DD; ++k) {
        float w0 = W[k * DD + j2];
        float w1 = W[k * DD + j2 + 64];
#pragma unroll
        for (int r = 0; r < 8; ++r) {
            float xv = sm[(g * 8 + r) * DD + k];
            acc0[r] = fmaf(xv, w0, acc0[r]);
            acc1[r] = fmaf(xv, w1, acc1[r]);
        }
    }

    const float b0 = bias[j2];
    const float b1 = bias[j2 + 64];
    float m0 = -3.402823466e38f, m1 = -3.402823466e38f;
#pragma unroll
    for (int r = 0; r < 8; ++r) {
        float v0 = acc0[r] + b0;
        float v1 = acc1[r] + b1;
        if (g * 8 + r < rows_here) {
            size_t row = (size_t)(block_row + g * 8 + r);
            out[row * DD + j2]      = v0;
            out[row * DD + j2 + 64] = v1;
            m0 = fmaxf(m0, v0);
            m1 = fmaxf(m1, v1);
        }
    }
    cmx[g][j2]      = m0;
    cmx[g][j2 + 64] = m1;
    __syncthreads();
    if (t < DD) {
        float mm = fmaxf(fmaxf(cmx[0][t], cmx[1][t]), fmaxf(cmx[2][t], cmx[3][t]));
        atomicMax(&colmax[t], fmap(mm));
    }
}

__global__ void finalize_kernel(const unsigned* __restrict__ colmax, float* __restrict__ pooled)
{
    int j = threadIdx.x;
    if (j < DD) pooled[j] = funmap(colmax[j]) + funmap(colmax[DD + j]);
}

extern "C" void kernel_launch(void* const* d_in, const int* in_sizes, int n_in,
                              void* d_out, int out_size, void* d_ws, size_t ws_size,
                              hipStream_t stream)
{
    const float* nf_in      = (const float*)d_in[0];
    const float* ef_in      = (const float*)d_in[1];
    const float* node_Wc    = (const float*)d_in[2];
    const float* node_bc    = (const float*)d_in[3];
    const float* node_Wn    = (const float*)d_in[4];
    const float* node_bn    = (const float*)d_in[5];
    const float* node_We    = (const float*)d_in[6];
    const float* node_be    = (const float*)d_in[7];
    const float* edge_Wc    = (const float*)d_in[8];
    const float* edge_bc    = (const float*)d_in[9];
    const float* edge_Wn    = (const float*)d_in[10];
    const float* edge_bn    = (const float*)d_in[11];
    const float* edge_We    = (const float*)d_in[12];
    const float* edge_be    = (const float*)d_in[13];
    const float* W_node_out = (const float*)d_in[14];
    const float* b_node_out = (const float*)d_in[15];
    const float* W_edge_out = (const float*)d_in[16];
    const float* b_edge_out = (const float*)d_in[17];
    const int* edge_index        = (const int*)d_in[18];
    const int* line_edge_index   = (const int*)d_in[19];
    const int* node_edge_index   = (const int*)d_in[20];
    const int* node_edge_scatter = (const int*)d_in[21];
    const int* edge_node_index   = (const int*)d_in[22];
    const int* edge_node_scatter = (const int*)d_in[23];

    const size_t ND = (size_t)NN * DD;
    const size_t ED = (size_t)EE * DD;

    // ---- workspace layout ----
    float* nfA = (float*)d_ws;
    float* nfB = nfA + ND;
    float* efA = nfB + ND;
    float* efB = efA + ED;
    int* ip = (int*)(efB + ED);
    // CSR N0 (node aggr from nf via edge_index)
    int* cntN0 = ip;             int* rsN0 = cntN0 + NN;  int* curN0 = rsN0 + NN + 1;  int* lstN0 = curN0 + NN;  ip = lstN0 + EE;
    // CSR N1 (node aggr1 from ef)
    int* cntN1 = ip;             int* rsN1 = cntN1 + NN;  int* curN1 = rsN1 + NN + 1;  int* lstN1 = curN1 + NN;  ip = lstN1 + EE;
    // CSR E0 (edge aggr from ef via line_edge_index)
    int* cntE0 = ip;             int* rsE0 = cntE0 + EE;  int* curE0 = rsE0 + EE + 1;  int* lstE0 = curE0 + EE;  ip = lstE0 + LL;
    // CSR E1 (edge aggr1 from nf)
    int* cntE1 = ip;             int* rsE1 = cntE1 + EE;  int* curE1 = rsE1 + EE + 1;  int* lstE1 = curE1 + EE;  ip = lstE1 + LL;
    unsigned* colmax = (unsigned*)ip;
    int* bsum = (int*)(colmax + 2 * DD);

    float* tn = (float*)d_out + DD;
    float* te = tn + ND;

    // ---- build 4 CSRs (indices are layer-invariant; once per call) ----
    auto build = [&](const int* dest, const int* srcv, int n, int m,
                     int* cnt, int* rs, int* cur, int* lst) {
        hipMemsetAsync(cnt, 0, (size_t)m * sizeof(int), stream);
        hist_kernel<<<(n + 255) / 256, 256, 0, stream>>>(dest, n, cnt);
        int nb = (m + 2047) / 2048;
        scan1_kernel<<<nb, 256, 0, stream>>>(cnt, m, rs, bsum);
        scan2_kernel<<<1, 512, 0, stream>>>(bsum, nb);
        scan3_kernel<<<(m + 1 + 255) / 256, 256, 0, stream>>>(rs, m, bsum, n);
        hipMemcpyAsync(cur, rs, (size_t)m * sizeof(int), hipMemcpyDeviceToDevice, stream);
        fill_kernel<<<(n + 255) / 256, 256, 0, stream>>>(dest, srcv, n, cur, lst);
    };
    build(edge_index + EE,    edge_index,      EE, NN, cntN0, rsN0, curN0, lstN0);
    build(node_edge_scatter,  node_edge_index, EE, NN, cntN1, rsN1, curN1, lstN1);
    build(line_edge_index + LL, line_edge_index, LL, EE, cntE0, rsE0, curE0, lstE0);
    build(edge_node_scatter,  edge_node_index, LL, EE, cntE1, rsE1, curE1, lstE1);

    const int gemmN_blocks = (NN + 31) / 32;
    const int gemmE_blocks = (EE + 31) / 32;

    // ---- 3 layers, ping-pong (both node & edge updates read OLD nf/ef) ----
    const float* nf = nf_in;
    const float* ef = ef_in;
    float* nfo[3] = { nfA, nfB, nfA };
    float* efo[3] = { efA, efB, efA };
    for (int i = 0; i < 3; ++i) {
        int act = (i < 2) ? 1 : 0;
        sage_fused_kernel<<<gemmN_blocks, 256, 0, stream>>>(
            nf, nf, rsN0, lstN0, ef, rsN1, lstN1,
            node_Wc + (size_t)i * WSZ, node_Wn + (size_t)i * WSZ, node_We + (size_t)i * WSZ,
            node_bc + (size_t)i * DD,  node_bn + (size_t)i * DD,  node_be + (size_t)i * DD,
            nfo[i], NN, act);
        sage_fused_kernel<<<gemmE_blocks, 256, 0, stream>>>(
            ef, ef, rsE0, lstE0, nf, rsE1, lstE1,
            edge_Wc + (size_t)i * WSZ, edge_Wn + (size_t)i * WSZ, edge_We + (size_t)i * WSZ,
            edge_bc + (size_t)i * DD,  edge_bn + (size_t)i * DD,  edge_be + (size_t)i * DD,
            efo[i], EE, act);
        nf = nfo[i];
        ef = efo[i];
    }

    hipMemsetAsync(colmax, 0, 2 * DD * sizeof(unsigned), stream);
    out_linear_kernel<<<gemmN_blocks, 256, 0, stream>>>(nf, W_node_out, b_node_out, tn, colmax, NN);
    out_linear_kernel<<<gemmE_blocks, 256, 0, stream>>>(ef, W_edge_out, b_edge_out, te, colmax + DD, EE);
    finalize_kernel<<<1, DD, 0, stream>>>(colmax, (float*)d_out);
}

// Round 5
// 4568.576 us; speedup vs baseline: 4.8141x; 1.7146x over previous
//
#include <hip/hip_runtime.h>

#define NN 50000
#define EE 800000
#define LL 800000
#define DD 128
#define WSZ (DD * DD)

typedef unsigned short u16;
typedef __attribute__((ext_vector_type(8))) short bf16x8;
typedef __attribute__((ext_vector_type(4))) float f32x4;

// ---------- conversions ----------
__device__ __forceinline__ float bf2f(u16 h) { return __uint_as_float(((unsigned)h) << 16); }
__device__ __forceinline__ u16 f2bf(float x) {
    unsigned u = __float_as_uint(x);
    return (u16)((u + 0x7fffu + ((u >> 16) & 1u)) >> 16);
}

// ---------- order-preserving float <-> uint map for atomic max ----------
__device__ __forceinline__ unsigned fmap(float x) {
    unsigned u = __float_as_uint(x);
    return (u & 0x80000000u) ? ~u : (u | 0x80000000u);
}
__device__ __forceinline__ float funmap(unsigned u) {
    return (u & 0x80000000u) ? __uint_as_float(u & 0x7fffffffu) : __uint_as_float(~u);
}

// ====================== dtype conversion kernels ======================
__global__ __launch_bounds__(256) void convert_f_kernel(
    const float* __restrict__ in, u16* __restrict__ out, int n4)
{
    int i = blockIdx.x * 256 + threadIdx.x;
    if (i < n4) {
        float4 v = reinterpret_cast<const float4*>(in)[i];
        ushort4 o;
        o.x = f2bf(v.x); o.y = f2bf(v.y); o.z = f2bf(v.z); o.w = f2bf(v.w);
        reinterpret_cast<ushort4*>(out)[i] = o;
    }
}

// Wt[n][k] = bf16(W[k][n]) per 128x128 matrix; grid = nmat blocks
__global__ __launch_bounds__(256) void convert_w_kernel(
    const float* __restrict__ W, u16* __restrict__ Wt)
{
    const float* w = W + (size_t)blockIdx.x * WSZ;
    u16* o = Wt + (size_t)blockIdx.x * WSZ;
    for (int i = threadIdx.x; i < WSZ; i += 256) {
        int n = i >> 7, k = i & 127;
        o[i] = f2bf(w[k * DD + n]);
    }
}

// ====================== CSR build ======================
__global__ __launch_bounds__(256) void hist_kernel(
    const int* __restrict__ dest, int n, int* __restrict__ cnt)
{
    int i = blockIdx.x * 256 + threadIdx.x;
    if (i < n) atomicAdd(&cnt[dest[i]], 1);
}

__global__ __launch_bounds__(256) void scan1_kernel(
    const int* __restrict__ in, int n, int* __restrict__ out, int* __restrict__ bsum)
{
    __shared__ int ts[256];
    const int tid = threadIdx.x;
    const int base = blockIdx.x * 2048 + tid * 8;
    int v[8]; int s = 0;
#pragma unroll
    for (int k = 0; k < 8; ++k) { v[k] = (base + k < n) ? in[base + k] : 0; s += v[k]; }
    ts[tid] = s;
    __syncthreads();
    for (int off = 1; off < 256; off <<= 1) {
        int y = (tid >= off) ? ts[tid - off] : 0;
        __syncthreads();
        ts[tid] += y;
        __syncthreads();
    }
    int excl = ts[tid] - s;
    if (tid == 255) bsum[blockIdx.x] = ts[255];
    int run = excl;
#pragma unroll
    for (int k = 0; k < 8; ++k) { if (base + k < n) out[base + k] = run; run += v[k]; }
}

__global__ __launch_bounds__(512) void scan2_kernel(int* bsum, int nb)
{
    __shared__ int ts[512];
    const int tid = threadIdx.x;
    int v = (tid < nb) ? bsum[tid] : 0;
    ts[tid] = v;
    __syncthreads();
    for (int off = 1; off < 512; off <<= 1) {
        int y = (tid >= off) ? ts[tid - off] : 0;
        __syncthreads();
        ts[tid] += y;
        __syncthreads();
    }
    if (tid < nb) bsum[tid] = ts[tid] - v;
}

__global__ __launch_bounds__(256) void scan3_kernel(
    int* __restrict__ rs, int m, const int* __restrict__ bsum, int total)
{
    int i = blockIdx.x * 256 + threadIdx.x;
    if (i < m) rs[i] += bsum[i >> 11];
    else if (i == m) rs[m] = total;
}

__global__ __launch_bounds__(256) void fill_kernel(
    const int* __restrict__ dest, const int* __restrict__ srcv, int n,
    int* __restrict__ cursor, int* __restrict__ list)
{
    int i = blockIdx.x * 256 + threadIdx.x;
    if (i < n) {
        int p = atomicAdd(&cursor[dest[i]], 1);
        list[p] = srcv[i];
    }
}

// ====================== fused sage via MFMA ======================
// Block = 256 thr = 4 waves; tile = 32 rows x 128 cols; wave g owns cols g*32..g*32+31.
// s=0: A-frags straight from global x (row-clamped). s=1/2: aggregation rows built in
// LDS (XOR-swizzled, G4) then consumed as ds_read_b128 A-frags.
// MFMA 16x16x32 bf16: A[m][k]: m=lane&15, k=(lane>>4)*8+j ; B[k][n]: n=lane&15, same k;
// D: row=(lane>>4)*4+r, col=lane&15  [m89 verified mapping].
__global__ __launch_bounds__(256) void sage_mfma_kernel(
    const u16* __restrict__ x,
    const u16* __restrict__ src0, const int* __restrict__ rs0, const int* __restrict__ ls0,
    const u16* __restrict__ src1, const int* __restrict__ rs1, const int* __restrict__ ls1,
    const u16* __restrict__ Wc, const u16* __restrict__ Wn, const u16* __restrict__ We,
    const float* __restrict__ bc, const float* __restrict__ bn, const float* __restrict__ be,
    u16* __restrict__ out, int M, int act)
{
    __shared__ char smb[32 * 256];
    __shared__ float partial[4][32];
    __shared__ float invs[32];
    const int t = threadIdx.x;
    const int lane = t & 63, g = t >> 6;
    const int l15 = lane & 15, l4 = lane >> 4;
    const int half = lane >> 5, l32 = lane & 31;
    const int block_row = blockIdx.x * 32;
    const int rows_here = min(32, M - block_row);
    const int n0 = g * 32 + l15;

    const f32x4 zero = {0.f, 0.f, 0.f, 0.f};
    f32x4 acc[2][2];
    acc[0][0] = zero; acc[0][1] = zero; acc[1][0] = zero; acc[1][1] = zero;

    // ---- source 0: x @ Wc (A direct from global) ----
    {
        const int ar0 = min(block_row + l15, M - 1);
        const int ar1 = min(block_row + 16 + l15, M - 1);
#pragma unroll
        for (int kk = 0; kk < 4; ++kk) {
            int ke = kk * 32 + l4 * 8;
            bf16x8 a0 = *reinterpret_cast<const bf16x8*>(x + (size_t)ar0 * DD + ke);
            bf16x8 a1 = *reinterpret_cast<const bf16x8*>(x + (size_t)ar1 * DD + ke);
            bf16x8 b0 = *reinterpret_cast<const bf16x8*>(Wc + (size_t)n0 * DD + ke);
            bf16x8 b1 = *reinterpret_cast<const bf16x8*>(Wc + (size_t)(n0 + 16) * DD + ke);
            acc[0][0] = __builtin_amdgcn_mfma_f32_16x16x32_bf16(a0, b0, acc[0][0], 0, 0, 0);
            acc[1][0] = __builtin_amdgcn_mfma_f32_16x16x32_bf16(a1, b0, acc[1][0], 0, 0, 0);
            acc[0][1] = __builtin_amdgcn_mfma_f32_16x16x32_bf16(a0, b1, acc[0][1], 0, 0, 0);
            acc[1][1] = __builtin_amdgcn_mfma_f32_16x16x32_bf16(a1, b1, acc[1][1], 0, 0, 0);
        }
    }

    // ---- sources 1,2: CSR gather-aggregate -> LDS -> MFMA ----
    for (int s = 1; s <= 2; ++s) {
        const u16* __restrict__ src = (s == 1) ? src0 : src1;
        const int* __restrict__ rs  = (s == 1) ? rs0  : rs1;
        const int* __restrict__ ls  = (s == 1) ? ls0  : ls1;
        const u16* __restrict__ w   = (s == 1) ? Wn   : We;

        __syncthreads();   // smb free (prev source's reads done)
        for (int rp = 0; rp < 4; ++rp) {
            int rr = g * 8 + rp * 2 + half;
            float4 a = make_float4(0.f, 0.f, 0.f, 0.f);
            if (rr < rows_here) {
                int d = block_row + rr;
                int beg = rs[d], end = rs[d + 1];
                for (int j = beg; j < end; ++j) {
                    const u16* p = src + (size_t)ls[j] * DD + l32 * 4;
                    ushort4 v = *reinterpret_cast<const ushort4*>(p);
                    a.x += bf2f(v.x); a.y += bf2f(v.y); a.z += bf2f(v.z); a.w += bf2f(v.w);
                }
            }
            ushort4 o;
            o.x = f2bf(a.x); o.y = f2bf(a.y); o.z = f2bf(a.z); o.w = f2bf(a.w);
            int off = (rr * 256 + l32 * 8) ^ ((rr & 7) << 4);
            *reinterpret_cast<ushort4*>(smb + off) = o;
        }
        __syncthreads();

#pragma unroll
        for (int kk = 0; kk < 4; ++kk) {
            int kb = kk * 64 + l4 * 16;
            int off0 = ((l15 * 256) + kb) ^ ((l15 & 7) << 4);
            int off1 = (((16 + l15) * 256) + kb) ^ ((l15 & 7) << 4);
            bf16x8 a0 = *reinterpret_cast<const bf16x8*>(smb + off0);
            bf16x8 a1 = *reinterpret_cast<const bf16x8*>(smb + off1);
            int ke = kk * 32 + l4 * 8;
            bf16x8 b0 = *reinterpret_cast<const bf16x8*>(w + (size_t)n0 * DD + ke);
            bf16x8 b1 = *reinterpret_cast<const bf16x8*>(w + (size_t)(n0 + 16) * DD + ke);
            acc[0][0] = __builtin_amdgcn_mfma_f32_16x16x32_bf16(a0, b0, acc[0][0], 0, 0, 0);
            acc[1][0] = __builtin_amdgcn_mfma_f32_16x16x32_bf16(a1, b0, acc[1][0], 0, 0, 0);
            acc[0][1] = __builtin_amdgcn_mfma_f32_16x16x32_bf16(a0, b1, acc[0][1], 0, 0, 0);
            acc[1][1] = __builtin_amdgcn_mfma_f32_16x16x32_bf16(a1, b1, acc[1][1], 0, 0, 0);
        }
    }

    // ---- epilogue: bias, row-L2-norm (cross-wave via LDS partials), act, store bf16 ----
    const int col0 = n0, col1 = n0 + 16;
    const float bs0 = bc[col0] + bn[col0] + be[col0];
    const float bs1 = bc[col1] + bn[col1] + be[col1];
    float vv[2][2][4];
    float ss[8];
#pragma unroll
    for (int a2 = 0; a2 < 2; ++a2)
#pragma unroll
        for (int r = 0; r < 4; ++r) {
            float v0 = acc[a2][0][r] + bs0;
            float v1 = acc[a2][1][r] + bs1;
            vv[a2][0][r] = v0; vv[a2][1][r] = v1;
            ss[a2 * 4 + r] = v0 * v0 + v1 * v1;
        }
#pragma unroll
    for (int m = 1; m <= 8; m <<= 1)
#pragma unroll
        for (int i = 0; i < 8; ++i) ss[i] += __shfl_xor(ss[i], m);
    if (l15 == 0) {
#pragma unroll
        for (int a2 = 0; a2 < 2; ++a2)
#pragma unroll
            for (int r = 0; r < 4; ++r)
                partial[g][a2 * 16 + l4 * 4 + r] = ss[a2 * 4 + r];
    }
    __syncthreads();
    if (t < 32) {
        float s = partial[0][t] + partial[1][t] + partial[2][t] + partial[3][t];
        invs[t] = 1.0f / fmaxf(sqrtf(s), 1e-12f);
    }
    __syncthreads();
#pragma unroll
    for (int a2 = 0; a2 < 2; ++a2)
#pragma unroll
        for (int r = 0; r < 4; ++r) {
            int row = a2 * 16 + l4 * 4 + r;
            float inv = invs[row];
            float v0 = vv[a2][0][r] * inv;
            float v1 = vv[a2][1][r] * inv;
            if (act) {
                v0 = v0 >= 0.f ? v0 : 0.01f * v0;
                v1 = v1 >= 0.f ? v1 : 0.01f * v1;
            }
            if (row < rows_here) {
                size_t ro = (size_t)(block_row + row) * DD;
                out[ro + col0] = f2bf(v0);
                out[ro + col1] = f2bf(v1);
            }
        }
}

// ====================== final linear via MFMA (+ col-max) ======================
__global__ __launch_bounds__(256) void out_mfma_kernel(
    const u16* __restrict__ x, const u16* __restrict__ Wt, const float* __restrict__ bias,
    float* __restrict__ out, unsigned* __restrict__ colmax, int M)
{
    const int t = threadIdx.x;
    const int lane = t & 63, g = t >> 6;
    const int l15 = lane & 15, l4 = lane >> 4;
    const int block_row = blockIdx.x * 32;
    const int rows_here = min(32, M - block_row);
    const int n0 = g * 32 + l15;

    const f32x4 zero = {0.f, 0.f, 0.f, 0.f};
    f32x4 acc[2][2];
    acc[0][0] = zero; acc[0][1] = zero; acc[1][0] = zero; acc[1][1] = zero;

    const int ar0 = min(block_row + l15, M - 1);
    const int ar1 = min(block_row + 16 + l15, M - 1);
#pragma unroll
    for (int kk = 0; kk < 4; ++kk) {
        int ke = kk * 32 + l4 * 8;
        bf16x8 a0 = *reinterpret_cast<const bf16x8*>(x + (size_t)ar0 * DD + ke);
        bf16x8 a1 = *reinterpret_cast<const bf16x8*>(x + (size_t)ar1 * DD + ke);
        bf16x8 b0 = *reinterpret_cast<const bf16x8*>(Wt + (size_t)n0 * DD + ke);
        bf16x8 b1 = *reinterpret_cast<const bf16x8*>(Wt + (size_t)(n0 + 16) * DD + ke);
        acc[0][0] = __builtin_amdgcn_mfma_f32_16x16x32_bf16(a0, b0, acc[0][0], 0, 0, 0);
        acc[1][0] = __builtin_amdgcn_mfma_f32_16x16x32_bf16(a1, b0, acc[1][0], 0, 0, 0);
        acc[0][1] = __builtin_amdgcn_mfma_f32_16x16x32_bf16(a0, b1, acc[0][1], 0, 0, 0);
        acc[1][1] = __builtin_amdgcn_mfma_f32_16x16x32_bf16(a1, b1, acc[1][1], 0, 0, 0);
    }

    const float b0v = bias[n0], b1v = bias[n0 + 16];
    float m0 = -3.402823466e38f, m1 = -3.402823466e38f;
#pragma unroll
    for (int a2 = 0; a2 < 2; ++a2)
#pragma unroll
        for (int r = 0; r < 4; ++r) {
            int row = a2 * 16 + l4 * 4 + r;
            float v0 = acc[a2][0][r] + b0v;
            float v1 = acc[a2][1][r] + b1v;
            if (row < rows_here) {
                size_t ro = (size_t)(block_row + row) * DD;
                out[ro + n0]      = v0;
                out[ro + n0 + 16] = v1;
                m0 = fmaxf(m0, v0);
                m1 = fmaxf(m1, v1);
            }
        }
    m0 = fmaxf(m0, __shfl_xor(m0, 16)); m0 = fmaxf(m0, __shfl_xor(m0, 32));
    m1 = fmaxf(m1, __shfl_xor(m1, 16)); m1 = fmaxf(m1, __shfl_xor(m1, 32));
    if (lane < 16) {
        atomicMax(&colmax[n0], fmap(m0));
        atomicMax(&colmax[n0 + 16], fmap(m1));
    }
}

__global__ void finalize_kernel(const unsigned* __restrict__ colmax, float* __restrict__ pooled)
{
    int j = threadIdx.x;
    if (j < DD) pooled[j] = funmap(colmax[j]) + funmap(colmax[DD + j]);
}

extern "C" void kernel_launch(void* const* d_in, const int* in_sizes, int n_in,
                              void* d_out, int out_size, void* d_ws, size_t ws_size,
                              hipStream_t stream)
{
    const float* nf_in      = (const float*)d_in[0];
    const float* ef_in      = (const float*)d_in[1];
    const float* node_Wc    = (const float*)d_in[2];
    const float* node_bc    = (const float*)d_in[3];
    const float* node_Wn    = (const float*)d_in[4];
    const float* node_bn    = (const float*)d_in[5];
    const float* node_We    = (const float*)d_in[6];
    const float* node_be    = (const float*)d_in[7];
    const float* edge_Wc    = (const float*)d_in[8];
    const float* edge_bc    = (const float*)d_in[9];
    const float* edge_Wn    = (const float*)d_in[10];
    const float* edge_bn    = (const float*)d_in[11];
    const float* edge_We    = (const float*)d_in[12];
    const float* edge_be    = (const float*)d_in[13];
    const float* W_node_out = (const float*)d_in[14];
    const float* b_node_out = (const float*)d_in[15];
    const float* W_edge_out = (const float*)d_in[16];
    const float* b_edge_out = (const float*)d_in[17];
    const int* edge_index        = (const int*)d_in[18];
    const int* line_edge_index   = (const int*)d_in[19];
    const int* node_edge_index   = (const int*)d_in[20];
    const int* node_edge_scatter = (const int*)d_in[21];
    const int* edge_node_index   = (const int*)d_in[22];
    const int* edge_node_scatter = (const int*)d_in[23];

    const size_t ND = (size_t)NN * DD;
    const size_t ED = (size_t)EE * DD;

    // ---- workspace layout (bf16 features, bf16 transposed weights, CSR ints) ----
    u16* nfA = (u16*)d_ws;
    u16* nfB = nfA + ND;
    u16* efA = nfB + ND;
    u16* efB = efA + ED;
    u16* wt  = efB + ED;          // 20 matrices of 128x128 bf16
    int* ip = (int*)(wt + 20 * WSZ);
    int* cntN0 = ip;  int* rsN0 = cntN0 + NN;  int* curN0 = rsN0 + NN + 1;  int* lstN0 = curN0 + NN;  ip = lstN0 + EE;
    int* cntN1 = ip;  int* rsN1 = cntN1 + NN;  int* curN1 = rsN1 + NN + 1;  int* lstN1 = curN1 + NN;  ip = lstN1 + EE;
    int* cntE0 = ip;  int* rsE0 = cntE0 + EE;  int* curE0 = rsE0 + EE + 1;  int* lstE0 = curE0 + EE;  ip = lstE0 + LL;
    int* cntE1 = ip;  int* rsE1 = cntE1 + EE;  int* curE1 = rsE1 + EE + 1;  int* lstE1 = curE1 + EE;  ip = lstE1 + LL;
    unsigned* colmax = (unsigned*)ip;
    int* bsum = (int*)(colmax + 2 * DD);

    float* tn = (float*)d_out + DD;
    float* te = tn + ND;

    // ---- convert inputs + weights to bf16 ----
    convert_f_kernel<<<(int)((ND / 4 + 255) / 256), 256, 0, stream>>>(nf_in, nfA, (int)(ND / 4));
    convert_f_kernel<<<(int)((ED / 4 + 255) / 256), 256, 0, stream>>>(ef_in, efA, (int)(ED / 4));
    convert_w_kernel<<<3, 256, 0, stream>>>(node_Wc, wt + (size_t)0  * WSZ);
    convert_w_kernel<<<3, 256, 0, stream>>>(node_Wn, wt + (size_t)3  * WSZ);
    convert_w_kernel<<<3, 256, 0, stream>>>(node_We, wt + (size_t)6  * WSZ);
    convert_w_kernel<<<3, 256, 0, stream>>>(edge_Wc, wt + (size_t)9  * WSZ);
    convert_w_kernel<<<3, 256, 0, stream>>>(edge_Wn, wt + (size_t)12 * WSZ);
    convert_w_kernel<<<3, 256, 0, stream>>>(edge_We, wt + (size_t)15 * WSZ);
    convert_w_kernel<<<1, 256, 0, stream>>>(W_node_out, wt + (size_t)18 * WSZ);
    convert_w_kernel<<<1, 256, 0, stream>>>(W_edge_out, wt + (size_t)19 * WSZ);

    // ---- build 4 CSRs (indices are layer-invariant) ----
    auto build = [&](const int* dest, const int* srcv, int n, int m,
                     int* cnt, int* rs, int* cur, int* lst) {
        hipMemsetAsync(cnt, 0, (size_t)m * sizeof(int), stream);
        hist_kernel<<<(n + 255) / 256, 256, 0, stream>>>(dest, n, cnt);
        int nb = (m + 2047) / 2048;
        scan1_kernel<<<nb, 256, 0, stream>>>(cnt, m, rs, bsum);
        scan2_kernel<<<1, 512, 0, stream>>>(bsum, nb);
        scan3_kernel<<<(m + 1 + 255) / 256, 256, 0, stream>>>(rs, m, bsum, n);
        hipMemcpyAsync(cur, rs, (size_t)m * sizeof(int), hipMemcpyDeviceToDevice, stream);
        fill_kernel<<<(n + 255) / 256, 256, 0, stream>>>(dest, srcv, n, cur, lst);
    };
    build(edge_index + EE,      edge_index,      EE, NN, cntN0, rsN0, curN0, lstN0);
    build(node_edge_scatter,    node_edge_index, EE, NN, cntN1, rsN1, curN1, lstN1);
    build(line_edge_index + LL, line_edge_index, LL, EE, cntE0, rsE0, curE0, lstE0);
    build(edge_node_scatter,    edge_node_index, LL, EE, cntE1, rsE1, curE1, lstE1);

    const int gemmN_blocks = (NN + 31) / 32;
    const int gemmE_blocks = (EE + 31) / 32;

    // ---- 3 layers, ping-pong A->B->A->B ----
    const u16* nf = nfA;
    const u16* ef = efA;
    u16* nfo[3] = { nfB, nfA, nfB };
    u16* efo[3] = { efB, efA, efB };
    for (int i = 0; i < 3; ++i) {
        int act = (i < 2) ? 1 : 0;
        sage_mfma_kernel<<<gemmN_blocks, 256, 0, stream>>>(
            nf, nf, rsN0, lstN0, ef, rsN1, lstN1,
            wt + (size_t)(0 + i) * WSZ, wt + (size_t)(3 + i) * WSZ, wt + (size_t)(6 + i) * WSZ,
            node_bc + (size_t)i * DD, node_bn + (size_t)i * DD, node_be + (size_t)i * DD,
            nfo[i], NN, act);
        sage_mfma_kernel<<<gemmE_blocks, 256, 0, stream>>>(
            ef, ef, rsE0, lstE0, nf, rsE1, lstE1,
            wt + (size_t)(9 + i) * WSZ, wt + (size_t)(12 + i) * WSZ, wt + (size_t)(15 + i) * WSZ,
            edge_bc + (size_t)i * DD, edge_bn + (size_t)i * DD, edge_be + (size_t)i * DD,
            efo[i], EE, act);
        nf = nfo[i];
        ef = efo[i];
    }

    hipMemsetAsync(colmax, 0, 2 * DD * sizeof(unsigned), stream);
    out_mfma_kernel<<<gemmN_blocks, 256, 0, stream>>>(nf, wt + (size_t)18 * WSZ, b_node_out, tn, colmax, NN);
    out_mfma_kernel<<<gemmE_blocks, 256, 0, stream>>>(ef, wt + (size_t)19 * WSZ, b_edge_out, te, colmax + DD, EE);
    finalize_kernel<<<1, DD, 0, stream>>>(colmax, (float*)d_out);
}

// Round 7
// 3903.069 us; speedup vs baseline: 5.6350x; 1.1705x over previous
//
#include <hip/hip_runtime.h>

#define NN 50000
#define EE 800000
#define LL 800000
#define DD 128
#define WSZ (DD * DD)

typedef unsigned short u16;
typedef __attribute__((ext_vector_type(8))) short bf16x8;
typedef __attribute__((ext_vector_type(4))) float f32x4;

__device__ __forceinline__ float bf2f(u16 h) { return __uint_as_float(((unsigned)h) << 16); }
__device__ __forceinline__ u16 f2bf(float x) {
    unsigned u = __float_as_uint(x);
    return (u16)((u + 0x7fffu + ((u >> 16) & 1u)) >> 16);
}
__device__ __forceinline__ unsigned fmap(float x) {
    unsigned u = __float_as_uint(x);
    return (u & 0x80000000u) ? ~u : (u | 0x80000000u);
}
__device__ __forceinline__ float funmap(unsigned u) {
    return (u & 0x80000000u) ? __uint_as_float(u & 0x7fffffffu) : __uint_as_float(~u);
}

// ====================== dtype conversion ======================
__global__ __launch_bounds__(256) void convert_f_kernel(
    const float* __restrict__ in, u16* __restrict__ out, int n4)
{
    int i = blockIdx.x * 256 + threadIdx.x;
    if (i < n4) {
        float4 v = reinterpret_cast<const float4*>(in)[i];
        ushort4 o;
        o.x = f2bf(v.x); o.y = f2bf(v.y); o.z = f2bf(v.z); o.w = f2bf(v.w);
        reinterpret_cast<ushort4*>(out)[i] = o;
    }
}

__global__ __launch_bounds__(256) void convert_w_kernel(
    const float* __restrict__ W, u16* __restrict__ Wt)
{
    const float* w = W + (size_t)blockIdx.x * WSZ;
    u16* o = Wt + (size_t)blockIdx.x * WSZ;
    for (int i = threadIdx.x; i < WSZ; i += 256) {
        int n = i >> 7, k = i & 127;
        o[i] = f2bf(w[k * DD + n]);
    }
}

// ====================== CSR build ======================
__global__ __launch_bounds__(256) void hist_kernel(
    const int* __restrict__ dest, int n, int* __restrict__ cnt)
{
    int i = blockIdx.x * 256 + threadIdx.x;
    if (i < n) atomicAdd(&cnt[dest[i]], 1);
}

__global__ __launch_bounds__(256) void scan1_kernel(
    const int* __restrict__ in, int n, int* __restrict__ out, int* __restrict__ bsum)
{
    __shared__ int ts[256];
    const int tid = threadIdx.x;
    const int base = blockIdx.x * 2048 + tid * 8;
    int v[8]; int s = 0;
#pragma unroll
    for (int k = 0; k < 8; ++k) { v[k] = (base + k < n) ? in[base + k] : 0; s += v[k]; }
    ts[tid] = s;
    __syncthreads();
    for (int off = 1; off < 256; off <<= 1) {
        int y = (tid >= off) ? ts[tid - off] : 0;
        __syncthreads();
        ts[tid] += y;
        __syncthreads();
    }
    int excl = ts[tid] - s;
    if (tid == 255) bsum[blockIdx.x] = ts[255];
    int run = excl;
#pragma unroll
    for (int k = 0; k < 8; ++k) { if (base + k < n) out[base + k] = run; run += v[k]; }
}

__global__ __launch_bounds__(512) void scan2_kernel(int* bsum, int nb)
{
    __shared__ int ts[512];
    const int tid = threadIdx.x;
    int v = (tid < nb) ? bsum[tid] : 0;
    ts[tid] = v;
    __syncthreads();
    for (int off = 1; off < 512; off <<= 1) {
        int y = (tid >= off) ? ts[tid - off] : 0;
        __syncthreads();
        ts[tid] += y;
        __syncthreads();
    }
    if (tid < nb) bsum[tid] = ts[tid] - v;
}

__global__ __launch_bounds__(256) void scan3_kernel(
    int* __restrict__ rs, int m, const int* __restrict__ bsum, int total)
{
    int i = blockIdx.x * 256 + threadIdx.x;
    if (i < m) rs[i] += bsum[i >> 11];
    else if (i == m) rs[m] = total;
}

__global__ __launch_bounds__(256) void fill_kernel(
    const int* __restrict__ dest, const int* __restrict__ srcv, int n,
    int* __restrict__ cursor, int* __restrict__ list)
{
    int i = blockIdx.x * 256 + threadIdx.x;
    if (i < n) {
        int p = atomicAdd(&cursor[dest[i]], 1);
        list[p] = srcv[i];
    }
}

// ====================== regular fused sage layer ======================
// 256 thr / 4 waves, 32 rows x 128 cols. All three sources go through the
// XOR-swizzled LDS tile (s=0 staged with fully coalesced 16B loads).
// Outputs staged in LDS (stride 132 u16) -> coalesced 8B global writes.
__global__ __launch_bounds__(256) void sage_mfma_kernel(
    const u16* __restrict__ x,
    const u16* __restrict__ src0, const int* __restrict__ rs0, const int* __restrict__ ls0,
    const u16* __restrict__ src1, const int* __restrict__ rs1, const int* __restrict__ ls1,
    const u16* __restrict__ Wc, const u16* __restrict__ Wn, const u16* __restrict__ We,
    const float* __restrict__ bc, const float* __restrict__ bn, const float* __restrict__ be,
    u16* __restrict__ out, int M, int act)
{
    __shared__ char smb[8448];          // 8192 swizzled A-tile, 8448 out bf16 tile (32x132 u16)
    __shared__ float partial[4][32];
    __shared__ float invs[32];
    const int t = threadIdx.x;
    const int lane = t & 63, g = t >> 6;
    const int l15 = lane & 15, l4 = lane >> 4;
    const int half = lane >> 5, l32 = lane & 31;
    const int block_row = blockIdx.x * 32;
    const int rows_here = min(32, M - block_row);
    const int n0 = g * 32 + l15;

    const f32x4 zero = {0.f, 0.f, 0.f, 0.f};
    f32x4 acc[2][2];
    acc[0][0] = zero; acc[0][1] = zero; acc[1][0] = zero; acc[1][1] = zero;

    for (int s = 0; s < 3; ++s) {
        if (s) __syncthreads();     // previous tile's reads complete before overwrite
        if (s == 0) {
            // coalesced stage of contiguous x tile (rows beyond M read in-ws garbage; unused)
            const u16* xt = x + (size_t)block_row * DD;
#pragma unroll
            for (int p = 0; p < 2; ++p) {
                int idx = p * 256 + t;
                int row = idx >> 4, c = idx & 15;
                uint4 v = *reinterpret_cast<const uint4*>(xt + (size_t)idx * 8);
                int off = (row * 256 + c * 16) ^ ((row & 7) << 4);
                *reinterpret_cast<uint4*>(smb + off) = v;
            }
        } else {
            const u16* __restrict__ src = (s == 1) ? src0 : src1;
            const int* __restrict__ rs  = (s == 1) ? rs0  : rs1;
            const int* __restrict__ ls  = (s == 1) ? ls0  : ls1;
            for (int rp = 0; rp < 4; ++rp) {
                int rr = g * 8 + rp * 2 + half;
                float4 a = make_float4(0.f, 0.f, 0.f, 0.f);
                if (rr < rows_here) {
                    int d = block_row + rr;
                    int beg = rs[d], end = rs[d + 1];
                    for (int j = beg; j < end; ++j) {
                        const u16* p = src + (size_t)ls[j] * DD + l32 * 4;
                        ushort4 v = *reinterpret_cast<const ushort4*>(p);
                        a.x += bf2f(v.x); a.y += bf2f(v.y); a.z += bf2f(v.z); a.w += bf2f(v.w);
                    }
                }
                ushort4 o;
                o.x = f2bf(a.x); o.y = f2bf(a.y); o.z = f2bf(a.z); o.w = f2bf(a.w);
                int off = (rr * 256 + l32 * 8) ^ ((rr & 7) << 4);
                *reinterpret_cast<ushort4*>(smb + off) = o;
            }
        }
        __syncthreads();
        const u16* __restrict__ w = (s == 0) ? Wc : ((s == 1) ? Wn : We);
#pragma unroll
        for (int kk = 0; kk < 4; ++kk) {
            int kb = kk * 64 + l4 * 16;
            int off0 = ((l15 * 256) + kb) ^ ((l15 & 7) << 4);
            int off1 = (((16 + l15) * 256) + kb) ^ ((l15 & 7) << 4);
            bf16x8 a0 = *reinterpret_cast<const bf16x8*>(smb + off0);
            bf16x8 a1 = *reinterpret_cast<const bf16x8*>(smb + off1);
            int ke = kk * 32 + l4 * 8;
            bf16x8 b0 = *reinterpret_cast<const bf16x8*>(w + (size_t)n0 * DD + ke);
            bf16x8 b1 = *reinterpret_cast<const bf16x8*>(w + (size_t)(n0 + 16) * DD + ke);
            acc[0][0] = __builtin_amdgcn_mfma_f32_16x16x32_bf16(a0, b0, acc[0][0], 0, 0, 0);
            acc[1][0] = __builtin_amdgcn_mfma_f32_16x16x32_bf16(a1, b0, acc[1][0], 0, 0, 0);
            acc[0][1] = __builtin_amdgcn_mfma_f32_16x16x32_bf16(a0, b1, acc[0][1], 0, 0, 0);
            acc[1][1] = __builtin_amdgcn_mfma_f32_16x16x32_bf16(a1, b1, acc[1][1], 0, 0, 0);
        }
    }

    // ---- epilogue: bias, row-L2-norm, act, LDS-stage, coalesced store ----
    const float bs0 = bc[n0] + bn[n0] + be[n0];
    const float bs1 = bc[n0 + 16] + bn[n0 + 16] + be[n0 + 16];
    float vv[2][2][4];
    float ss[8];
#pragma unroll
    for (int a2 = 0; a2 < 2; ++a2)
#pragma unroll
        for (int r = 0; r < 4; ++r) {
            float v0 = acc[a2][0][r] + bs0;
            float v1 = acc[a2][1][r] + bs1;
            vv[a2][0][r] = v0; vv[a2][1][r] = v1;
            ss[a2 * 4 + r] = v0 * v0 + v1 * v1;
        }
#pragma unroll
    for (int m = 1; m <= 8; m <<= 1)
#pragma unroll
        for (int i = 0; i < 8; ++i) ss[i] += __shfl_xor(ss[i], m);
    if (l15 == 0) {
#pragma unroll
        for (int a2 = 0; a2 < 2; ++a2)
#pragma unroll
            for (int r = 0; r < 4; ++r)
                partial[g][a2 * 16 + l4 * 4 + r] = ss[a2 * 4 + r];
    }
    __syncthreads();                 // also guarantees all smb A-frag reads done
    if (t < 32) {
        float s = partial[0][t] + partial[1][t] + partial[2][t] + partial[3][t];
        invs[t] = 1.0f / fmaxf(sqrtf(s), 1e-12f);
    }
    __syncthreads();

    u16* ot = (u16*)smb;             // 32 rows x stride 132
#pragma unroll
    for (int a2 = 0; a2 < 2; ++a2)
#pragma unroll
        for (int r = 0; r < 4; ++r) {
            int row = a2 * 16 + l4 * 4 + r;
            float inv = invs[row];
            float v0 = vv[a2][0][r] * inv;
            float v1 = vv[a2][1][r] * inv;
            if (act) {
                v0 = v0 >= 0.f ? v0 : 0.01f * v0;
                v1 = v1 >= 0.f ? v1 : 0.01f * v1;
            }
            ot[row * 132 + n0]      = f2bf(v0);
            ot[row * 132 + n0 + 16] = f2bf(v1);
        }
    __syncthreads();
#pragma unroll
    for (int p = 0; p < 4; ++p) {
        int idx = p * 256 + t;
        int row = idx >> 5, c = idx & 31;
        if (row < rows_here)
            *reinterpret_cast<ushort4*>(out + (size_t)(block_row + row) * DD + c * 4)
                = *reinterpret_cast<const ushort4*>(ot + row * 132 + c * 4);
    }
}

// ====================== final layer fused with output linear ======================
// Same as sage_mfma_kernel (act=0) but instead of writing features, the normalized
// bf16 tile goes back into swizzled LDS, a second MFMA GEMM vs W_out runs, and the
// f32 result is written coalesced (via stride-132 f32 LDS stage) + column-max.
__global__ __launch_bounds__(256) void sage_out_mfma_kernel(
    const u16* __restrict__ x,
    const u16* __restrict__ src0, const int* __restrict__ rs0, const int* __restrict__ ls0,
    const u16* __restrict__ src1, const int* __restrict__ rs1, const int* __restrict__ ls1,
    const u16* __restrict__ Wc, const u16* __restrict__ Wn, const u16* __restrict__ We,
    const float* __restrict__ bc, const float* __restrict__ bn, const float* __restrict__ be,
    const u16* __restrict__ Wo, const float* __restrict__ bo,
    float* __restrict__ tout, unsigned* __restrict__ colmax, int M)
{
    __shared__ char smb[16896];      // 8192 swizzled bf16 tile / 16896 f32 stage (32x132 f32)
    __shared__ float partial[4][32];
    __shared__ float invs[32];
    const int t = threadIdx.x;
    const int lane = t & 63, g = t >> 6;
    const int l15 = lane & 15, l4 = lane >> 4;
    const int half = lane >> 5, l32 = lane & 31;
    const int block_row = blockIdx.x * 32;
    const int rows_here = min(32, M - block_row);
    const int n0 = g * 32 + l15;

    const f32x4 zero = {0.f, 0.f, 0.f, 0.f};
    f32x4 acc[2][2];
    acc[0][0] = zero; acc[0][1] = zero; acc[1][0] = zero; acc[1][1] = zero;

    for (int s = 0; s < 3; ++s) {
        if (s) __syncthreads();
        if (s == 0) {
            const u16* xt = x + (size_t)block_row * DD;
#pragma unroll
            for (int p = 0; p < 2; ++p) {
                int idx = p * 256 + t;
                int row = idx >> 4, c = idx & 15;
                uint4 v = *reinterpret_cast<const uint4*>(xt + (size_t)idx * 8);
                int off = (row * 256 + c * 16) ^ ((row & 7) << 4);
                *reinterpret_cast<uint4*>(smb + off) = v;
            }
        } else {
            const u16* __restrict__ src = (s == 1) ? src0 : src1;
            const int* __restrict__ rs  = (s == 1) ? rs0  : rs1;
            const int* __restrict__ ls  = (s == 1) ? ls0  : ls1;
            for (int rp = 0; rp < 4; ++rp) {
                int rr = g * 8 + rp * 2 + half;
                float4 a = make_float4(0.f, 0.f, 0.f, 0.f);
                if (rr < rows_here) {
                    int d = block_row + rr;
                    int beg = rs[d], end = rs[d + 1];
                    for (int j = beg; j < end; ++j) {
                        const u16* p = src + (size_t)ls[j] * DD + l32 * 4;
                        ushort4 v = *reinterpret_cast<const ushort4*>(p);
                        a.x += bf2f(v.x); a.y += bf2f(v.y); a.z += bf2f(v.z); a.w += bf2f(v.w);
                    }
                }
                ushort4 o;
                o.x = f2bf(a.x); o.y = f2bf(a.y); o.z = f2bf(a.z); o.w = f2bf(a.w);
                int off = (rr * 256 + l32 * 8) ^ ((rr & 7) << 4);
                *reinterpret_cast<ushort4*>(smb + off) = o;
            }
        }
        __syncthreads();
        const u16* __restrict__ w = (s == 0) ? Wc : ((s == 1) ? Wn : We);
#pragma unroll
        for (int kk = 0; kk < 4; ++kk) {
            int kb = kk * 64 + l4 * 16;
            int off0 = ((l15 * 256) + kb) ^ ((l15 & 7) << 4);
            int off1 = (((16 + l15) * 256) + kb) ^ ((l15 & 7) << 4);
            bf16x8 a0 = *reinterpret_cast<const bf16x8*>(smb + off0);
            bf16x8 a1 = *reinterpret_cast<const bf16x8*>(smb + off1);
            int ke = kk * 32 + l4 * 8;
            bf16x8 b0 = *reinterpret_cast<const bf16x8*>(w + (size_t)n0 * DD + ke);
            bf16x8 b1 = *reinterpret_cast<const bf16x8*>(w + (size_t)(n0 + 16) * DD + ke);
            acc[0][0] = __builtin_amdgcn_mfma_f32_16x16x32_bf16(a0, b0, acc[0][0], 0, 0, 0);
            acc[1][0] = __builtin_amdgcn_mfma_f32_16x16x32_bf16(a1, b0, acc[1][0], 0, 0, 0);
            acc[0][1] = __builtin_amdgcn_mfma_f32_16x16x32_bf16(a0, b1, acc[0][1], 0, 0, 0);
            acc[1][1] = __builtin_amdgcn_mfma_f32_16x16x32_bf16(a1, b1, acc[1][1], 0, 0, 0);
        }
    }

    // ---- normalize (no act), restage swizzled bf16 ----
    const float bs0 = bc[n0] + bn[n0] + be[n0];
    const float bs1 = bc[n0 + 16] + bn[n0 + 16] + be[n0 + 16];
    float vv[2][2][4];
    float ss[8];
#pragma unroll
    for (int a2 = 0; a2 < 2; ++a2)
#pragma unroll
        for (int r = 0; r < 4; ++r) {
            float v0 = acc[a2][0][r] + bs0;
            float v1 = acc[a2][1][r] + bs1;
            vv[a2][0][r] = v0; vv[a2][1][r] = v1;
            ss[a2 * 4 + r] = v0 * v0 + v1 * v1;
        }
#pragma unroll
    for (int m = 1; m <= 8; m <<= 1)
#pragma unroll
        for (int i = 0; i < 8; ++i) ss[i] += __shfl_xor(ss[i], m);
    if (l15 == 0) {
#pragma unroll
        for (int a2 = 0; a2 < 2; ++a2)
#pragma unroll
            for (int r = 0; r < 4; ++r)
                partial[g][a2 * 16 + l4 * 4 + r] = ss[a2 * 4 + r];
    }
    __syncthreads();
    if (t < 32) {
        float s = partial[0][t] + partial[1][t] + partial[2][t] + partial[3][t];
        invs[t] = 1.0f / fmaxf(sqrtf(s), 1e-12f);
    }
    __syncthreads();
#pragma unroll
    for (int a2 = 0; a2 < 2; ++a2)
#pragma unroll
        for (int r = 0; r < 4; ++r) {
            int row = a2 * 16 + l4 * 4 + r;
            float inv = invs[row];
            int o0 = (row * 256 + n0 * 2) ^ ((row & 7) << 4);
            int o1 = (row * 256 + (n0 + 16) * 2) ^ ((row & 7) << 4);
            *reinterpret_cast<u16*>(smb + o0) = f2bf(vv[a2][0][r] * inv);
            *reinterpret_cast<u16*>(smb + o1) = f2bf(vv[a2][1][r] * inv);
        }
    __syncthreads();

    // ---- second GEMM: normalized tile @ Wo ----
    f32x4 acc2[2][2];
    acc2[0][0] = zero; acc2[0][1] = zero; acc2[1][0] = zero; acc2[1][1] = zero;
#pragma unroll
    for (int kk = 0; kk < 4; ++kk) {
        int kb = kk * 64 + l4 * 16;
        int off0 = ((l15 * 256) + kb) ^ ((l15 & 7) << 4);
        int off1 = (((16 + l15) * 256) + kb) ^ ((l15 & 7) << 4);
        bf16x8 a0 = *reinterpret_cast<const bf16x8*>(smb + off0);
        bf16x8 a1 = *reinterpret_cast<const bf16x8*>(smb + off1);
        int ke = kk * 32 + l4 * 8;
        bf16x8 b0 = *reinterpret_cast<const bf16x8*>(Wo + (size_t)n0 * DD + ke);
        bf16x8 b1 = *reinterpret_cast<const bf16x8*>(Wo + (size_t)(n0 + 16) * DD + ke);
        acc2[0][0] = __builtin_amdgcn_mfma_f32_16x16x32_bf16(a0, b0, acc2[0][0], 0, 0, 0);
        acc2[1][0] = __builtin_amdgcn_mfma_f32_16x16x32_bf16(a1, b0, acc2[1][0], 0, 0, 0);
        acc2[0][1] = __builtin_amdgcn_mfma_f32_16x16x32_bf16(a0, b1, acc2[0][1], 0, 0, 0);
        acc2[1][1] = __builtin_amdgcn_mfma_f32_16x16x32_bf16(a1, b1, acc2[1][1], 0, 0, 0);
    }

    // ---- bias, colmax, f32 stage, coalesced write ----
    const float b0v = bo[n0], b1v = bo[n0 + 16];
    float m0 = -3.402823466e38f, m1 = -3.402823466e38f;
    float* ft = (float*)smb;
    __syncthreads();                 // all second-GEMM A-frag reads done
#pragma unroll
    for (int a2 = 0; a2 < 2; ++a2)
#pragma unroll
        for (int r = 0; r < 4; ++r) {
            int row = a2 * 16 + l4 * 4 + r;
            float v0 = acc2[a2][0][r] + b0v;
            float v1 = acc2[a2][1][r] + b1v;
            ft[row * 132 + n0]      = v0;
            ft[row * 132 + n0 + 16] = v1;
            if (row < rows_here) { m0 = fmaxf(m0, v0); m1 = fmaxf(m1, v1); }
        }
    m0 = fmaxf(m0, __shfl_xor(m0, 16)); m0 = fmaxf(m0, __shfl_xor(m0, 32));
    m1 = fmaxf(m1, __shfl_xor(m1, 16)); m1 = fmaxf(m1, __shfl_xor(m1, 32));
    if (lane < 16) {
        atomicMax(&colmax[n0], fmap(m0));
        atomicMax(&colmax[n0 + 16], fmap(m1));
    }
    __syncthreads();
#pragma unroll
    for (int p = 0; p < 4; ++p) {
        int idx = p * 256 + t;
        int row = idx >> 5, c = idx & 31;
        if (row < rows_here)
            *reinterpret_cast<float4*>(tout + (size_t)(block_row + row) * DD + c * 4)
                = *reinterpret_cast<const float4*>(ft + row * 132 + c * 4);
    }
}

__global__ void finalize_kernel(const unsigned* __restrict__ colmax, float* __restrict__ pooled)
{
    int j = threadIdx.x;
    if (j < DD) pooled[j] = funmap(colmax[j]) + funmap(colmax[DD + j]);
}

extern "C" void kernel_launch(void* const* d_in, const int* in_sizes, int n_in,
                              void* d_out, int out_size, void* d_ws, size_t ws_size,
                              hipStream_t stream)
{
    const float* nf_in      = (const float*)d_in[0];
    const float* ef_in      = (const float*)d_in[1];
    const float* node_Wc    = (const float*)d_in[2];
    const float* node_bc    = (const float*)d_in[3];
    const float* node_Wn    = (const float*)d_in[4];
    const float* node_bn    = (const float*)d_in[5];
    const float* node_We    = (const float*)d_in[6];
    const float* node_be    = (const float*)d_in[7];
    const float* edge_Wc    = (const float*)d_in[8];
    const float* edge_bc    = (const float*)d_in[9];
    const float* edge_Wn    = (const float*)d_in[10];
    const float* edge_bn    = (const float*)d_in[11];
    const float* edge_We    = (const float*)d_in[12];
    const float* edge_be    = (const float*)d_in[13];
    const float* W_node_out = (const float*)d_in[14];
    const float* b_node_out = (const float*)d_in[15];
    const float* W_edge_out = (const float*)d_in[16];
    const float* b_edge_out = (const float*)d_in[17];
    const int* edge_index        = (const int*)d_in[18];
    const int* line_edge_index   = (const int*)d_in[19];
    const int* node_edge_index   = (const int*)d_in[20];
    const int* node_edge_scatter = (const int*)d_in[21];
    const int* edge_node_index   = (const int*)d_in[22];
    const int* edge_node_scatter = (const int*)d_in[23];

    const size_t ND = (size_t)NN * DD;
    const size_t ED = (size_t)EE * DD;

    u16* nfA = (u16*)d_ws;
    u16* nfB = nfA + ND;
    u16* efA = nfB + ND;
    u16* efB = efA + ED;
    u16* wt  = efB + ED;          // 20 matrices of 128x128 bf16
    int* ip = (int*)(wt + 20 * WSZ);
    int* cntN0 = ip;  int* rsN0 = cntN0 + NN;  int* curN0 = rsN0 + NN + 1;  int* lstN0 = curN0 + NN;  ip = lstN0 + EE;
    int* cntN1 = ip;  int* rsN1 = cntN1 + NN;  int* curN1 = rsN1 + NN + 1;  int* lstN1 = curN1 + NN;  ip = lstN1 + EE;
    int* cntE0 = ip;  int* rsE0 = cntE0 + EE;  int* curE0 = rsE0 + EE + 1;  int* lstE0 = curE0 + EE;  ip = lstE0 + LL;
    int* cntE1 = ip;  int* rsE1 = cntE1 + EE;  int* curE1 = rsE1 + EE + 1;  int* lstE1 = curE1 + EE;  ip = lstE1 + LL;
    unsigned* colmax = (unsigned*)ip;
    int* bsum = (int*)(colmax + 2 * DD);

    float* tn = (float*)d_out + DD;
    float* te = tn + ND;

    convert_f_kernel<<<(int)((ND / 4 + 255) / 256), 256, 0, stream>>>(nf_in, nfA, (int)(ND / 4));
    convert_f_kernel<<<(int)((ED / 4 + 255) / 256), 256, 0, stream>>>(ef_in, efA, (int)(ED / 4));
    convert_w_kernel<<<3, 256, 0, stream>>>(node_Wc, wt + (size_t)0  * WSZ);
    convert_w_kernel<<<3, 256, 0, stream>>>(node_Wn, wt + (size_t)3  * WSZ);
    convert_w_kernel<<<3, 256, 0, stream>>>(node_We, wt + (size_t)6  * WSZ);
    convert_w_kernel<<<3, 256, 0, stream>>>(edge_Wc, wt + (size_t)9  * WSZ);
    convert_w_kernel<<<3, 256, 0, stream>>>(edge_Wn, wt + (size_t)12 * WSZ);
    convert_w_kernel<<<3, 256, 0, stream>>>(edge_We, wt + (size_t)15 * WSZ);
    convert_w_kernel<<<1, 256, 0, stream>>>(W_node_out, wt + (size_t)18 * WSZ);
    convert_w_kernel<<<1, 256, 0, stream>>>(W_edge_out, wt + (size_t)19 * WSZ);

    auto build = [&](const int* dest, const int* srcv, int n, int m,
                     int* cnt, int* rs, int* cur, int* lst) {
        hipMemsetAsync(cnt, 0, (size_t)m * sizeof(int), stream);
        hist_kernel<<<(n + 255) / 256, 256, 0, stream>>>(dest, n, cnt);
        int nb = (m + 2047) / 2048;
        scan1_kernel<<<nb, 256, 0, stream>>>(cnt, m, rs, bsum);
        scan2_kernel<<<1, 512, 0, stream>>>(bsum, nb);
        scan3_kernel<<<(m + 1 + 255) / 256, 256, 0, stream>>>(rs, m, bsum, n);
        hipMemcpyAsync(cur, rs, (size_t)m * sizeof(int), hipMemcpyDeviceToDevice, stream);
        fill_kernel<<<(n + 255) / 256, 256, 0, stream>>>(dest, srcv, n, cur, lst);
    };
    build(edge_index + EE,      edge_index,      EE, NN, cntN0, rsN0, curN0, lstN0);
    build(node_edge_scatter,    node_edge_index, EE, NN, cntN1, rsN1, curN1, lstN1);
    build(line_edge_index + LL, line_edge_index, LL, EE, cntE0, rsE0, curE0, lstE0);
    build(edge_node_scatter,    edge_node_index, LL, EE, cntE1, rsE1, curE1, lstE1);

    const int gemmN_blocks = (NN + 31) / 32;
    const int gemmE_blocks = (EE + 31) / 32;

    // layers 0,1: regular; layer 2 fused with output linear
    const u16* nf = nfA;
    const u16* ef = efA;
    u16* nfo[2] = { nfB, nfA };
    u16* efo[2] = { efB, efA };
    for (int i = 0; i < 2; ++i) {
        sage_mfma_kernel<<<gemmN_blocks, 256, 0, stream>>>(
            nf, nf, rsN0, lstN0, ef, rsN1, lstN1,
            wt + (size_t)(0 + i) * WSZ, wt + (size_t)(3 + i) * WSZ, wt + (size_t)(6 + i) * WSZ,
            node_bc + (size_t)i * DD, node_bn + (size_t)i * DD, node_be + (size_t)i * DD,
            nfo[i], NN, 1);
        sage_mfma_kernel<<<gemmE_blocks, 256, 0, stream>>>(
            ef, ef, rsE0, lstE0, nf, rsE1, lstE1,
            wt + (size_t)(9 + i) * WSZ, wt + (size_t)(12 + i) * WSZ, wt + (size_t)(15 + i) * WSZ,
            edge_bc + (size_t)i * DD, edge_bn + (size_t)i * DD, edge_be + (size_t)i * DD,
            efo[i], EE, 1);
        nf = nfo[i];
        ef = efo[i];
    }

    hipMemsetAsync(colmax, 0, 2 * DD * sizeof(unsigned), stream);
    sage_out_mfma_kernel<<<gemmN_blocks, 256, 0, stream>>>(
        nf, nf, rsN0, lstN0, ef, rsN1, lstN1,
        wt + (size_t)2 * WSZ, wt + (size_t)5 * WSZ, wt + (size_t)8 * WSZ,
        node_bc + (size_t)2 * DD, node_bn + (size_t)2 * DD, node_be + (size_t)2 * DD,
        wt + (size_t)18 * WSZ, b_node_out, tn, colmax, NN);
    sage_out_mfma_kernel<<<gemmE_blocks, 256, 0, stream>>>(
        ef, ef, rsE0, lstE0, nf, rsE1, lstE1,
        wt + (size_t)11 * WSZ, wt + (size_t)14 * WSZ, wt + (size_t)17 * WSZ,
        edge_bc + (size_t)2 * DD, edge_bn + (size_t)2 * DD, edge_be + (size_t)2 * DD,
        wt + (size_t)19 * WSZ, b_edge_out, te, colmax + DD, EE);
    finalize_kernel<<<1, DD, 0, stream>>>(colmax, (float*)d_out);
}